// Round 10
// baseline (186.088 us; speedup 1.0000x reference)
//
#include <hip/hip_runtime.h>
#include <hip/hip_bf16.h>

// Problem constants
#define NB 256
#define NACT 21
#define NA 8192
#define NE 262144
#define CSR_CAP 128
#define LOG2E 1.44269504f

#if __has_builtin(__builtin_amdgcn_exp2f)
#define EXP2F(x) __builtin_amdgcn_exp2f(x)
#else
#define EXP2F(x) exp2f(x)
#endif

typedef __attribute__((ext_vector_type(8))) short short8;
typedef __attribute__((ext_vector_type(4))) float float4v;

// Module-global degree counters. Zero-initialized at module load; PROTOCOL:
// k_msg (last kernel) re-zeroes every row it owns at the end of each iteration,
// so every kernel_launch begins with g_cnt == 0. Lives outside d_ws on purpose
// (d_ws is re-poisoned between iterations; everything we keep in d_ws is fully
// rewritten before being read each iteration).
__device__ int g_cnt[NA];

__device__ inline float wsum64(float v) {
#pragma unroll
  for (int m = 32; m > 0; m >>= 1) v += __shfl_xor(v, m, 64);
  return v;
}

__device__ inline unsigned short f2bf(float f) {
  union { __hip_bfloat16 h; unsigned short u; } cv;
  cv.h = __float2bfloat16(f);
  return cv.u;
}

// ---------------- K1 k_ip: conv1+im2col (0..255) | CSR (256..767) | c2w cvt (768..803)
// ----------------          | prep fcw/w2t/wpart (804..1315) | hidden0 partials (1316..1323) ----------------
__global__ __launch_bounds__(512, 2) void k_ip(
    const float* __restrict__ x, const float* __restrict__ c1w, const float* __restrict__ c1b_,
    const float* __restrict__ c2w, const float* __restrict__ c2b, const float* __restrict__ fcw,
    const float* __restrict__ g2w, const float* __restrict__ g2b, const int* __restrict__ edges,
    unsigned short* c1b, unsigned short* w2abf, int* csr,
    unsigned short* fcwbf, unsigned short* w2t, float* wpart, float* h0p) {
  __shared__ float sm[3565];  // conv: xs[845] w1s[1440] c1s[1152] h0s[128]; prep: red[16][17]+b2s[16]
  int t = threadIdx.x, b = blockIdx.x;
  if (b >= 256 && b < 768) {  // ---- CSR build (g_cnt zeroed by protocol) ----
    int e = (b - 256) * 512 + t;
    int s = edges[2 * e], d = edges[2 * e + 1];
    int slot = atomicAdd(&g_cnt[d], 1);
    if (slot < CSR_CAP) csr[d * CSR_CAP + slot] = s;
    return;
  }
  if (b >= 768 && b < 804) {  // c2w -> bf16 (64*288 = 18432 values)
    int i = (b - 768) * 512 + t;
    w2abf[i] = f2bf(c2w[i]);
    return;
  }
  if (b >= 804 && b < 1316) {  // ---- prep: fcw->bf16, W2 transpose + partials ----
    float (*red)[17] = (float(*)[17])sm;
    float* b2s = sm + 272;
    int blk = b - 804;
    {  // fcw -> bf16: 2 floats per thread
      int base = (blk * 512 + t) * 2;
      float2 v = *(const float2*)&fcw[base];
      fcwbf[base + 0] = f2bf(v.x);
      fcwbf[base + 1] = f2bf(v.y);
    }
    {  // W2: block owns 16 cols; w2t[j][k] = W2[k][j] bf16; column partial sums
      if (t < 256) {
        int jj = t >> 4, k = t & 15;
        int j = blk * 16 + jj;
        float w = g2w[k * 8192 + j];
        w2t[j * 16 + k] = f2bf(w);
        red[jj][k] = w;
      }
      if (t < 16) b2s[t] = g2b[blk * 16 + t];
      __syncthreads();
      if (t < 16) {
        float s = 0.0f;
#pragma unroll
        for (int q = 0; q < 16; q++) s += red[q][t];
        wpart[blk * 17 + t] = s;
      } else if (t == 16) {
        float s = 0.0f;
#pragma unroll
        for (int q = 0; q < 16; q++) s += b2s[q];
        wpart[blk * 17 + 16] = s;
      }
    }
    return;
  }
  // ---- conv1 blocks (b<256: image b) and h0p blocks (b>=1316: image 0, fp32 path) ----
  int img = (b < 256) ? b : 0;
  float* xs = sm;
  float* w1s = sm + 845;
  float* c1s = sm + 2285;
  float* h0s = sm + 3437;  // 128 (h0p blocks only)
  for (int i = t; i < 845; i += 512) xs[i] = x[img * 845 + i];
  for (int i = t; i < 1440; i += 512) w1s[i] = c1w[i];
  __syncthreads();
  for (int idx = t; idx < 1152; idx += 512) {
    int oc = idx / 36, p = idx - oc * 36;
    int oy = p / 6, ox = p - oy * 6;
    float acc = c1b_[oc];
    const float* wp = &w1s[oc * 45];
#pragma unroll
    for (int ic = 0; ic < 5; ic++)
#pragma unroll
      for (int ky = 0; ky < 3; ky++)
#pragma unroll
        for (int kx = 0; kx < 3; kx++)
          acc += xs[ic * 169 + (oy * 2 + ky) * 13 + ox * 2 + kx] * wp[ic * 9 + ky * 3 + kx];
    c1s[idx] = fmaxf(acc, 0.0f);
  }
  __syncthreads();
  if (b < 256) {  // im2col: c1b[(b*16+p)*288 + k]
    for (int i = t; i < 4608; i += 512) {
      int p = i / 288, k = i - p * 288;
      int ic = k / 9, r = k - ic * 9;
      int ky = r / 3, kx = r - ky * 3;
      int oy = p >> 2, ox = p & 3;
      c1b[b * 4608 + i] = f2bf(c1s[ic * 36 + (oy + ky) * 6 + ox + kx]);
    }
    return;
  }
  // ---- hidden0 partial q = b-1316: conv2 (8 ocs, fp32) + partial FC over k in [q*128,q*128+128) ----
  int q = b - 1316;
  if (t < 128) {
    int ocl = t >> 4, pos = t & 15;
    int oc = q * 8 + ocl;
    int oy = pos >> 2, ox = pos & 3;
    float acc = c2b[oc];
    const float* wp = &c2w[oc * 288];
#pragma unroll
    for (int ic = 0; ic < 32; ic++)
#pragma unroll
      for (int ky = 0; ky < 3; ky++)
#pragma unroll
        for (int kx = 0; kx < 3; kx++)
          acc += c1s[ic * 36 + (oy + ky) * 6 + ox + kx] * wp[ic * 9 + ky * 3 + kx];
    h0s[t] = fmaxf(acc, 0.0f);  // h1024[0][oc*16+pos] for oc-range
  }
  __syncthreads();
  {  // partial: thread gc over 512 outputs, 128 MACs each (fcw row chunk contiguous)
    float p = 0.0f;
    const float* fr = &fcw[t * 1024 + q * 128];
#pragma unroll 4
    for (int j = 0; j < 128; j += 4) {
      float4 f4 = *(const float4*)&fr[j];
      p += f4.x * h0s[j] + f4.y * h0s[j + 1] + f4.z * h0s[j + 2] + f4.w * h0s[j + 3];
    }
    h0p[q * 512 + t] = p;
  }
}

// ---------------- K2 k_cf: conv2+fc fused tiles (0..511) | wsf (512) | enc+xe+dinv (513..1024) ----------------
__global__ __launch_bounds__(512, 2) void k_cf(
    const unsigned short* __restrict__ c1b, const unsigned short* __restrict__ w2abf,
    const float* __restrict__ c2b, const unsigned short* __restrict__ fcwbf,
    const float* __restrict__ fcb, const float* __restrict__ wpart,
    const float* __restrict__ h0p, const float* __restrict__ msgw,
    const float* __restrict__ msgb, const float* __restrict__ x_msg,
    float* hidden, float* wsf, float2* xe, float* dinv) {
  __shared__ __align__(16) unsigned short hs[16384];   // h tile [16 imgs][1024] bf16 (32 KB)
  __shared__ __align__(16) unsigned short w2a[18432];  // staged W2A [64][288] bf16 (36 KB)
  __shared__ float red[2048];                          // [8][256] fc reduce / wsf parts (8 KB)
  int t = threadIdx.x, blk = blockIdx.x;
  int wave = t >> 6, lane = t & 63;
  int m = lane & 15, quad = lane >> 4;
  if (blk == 512) {  // ---- wsf reduce ----
    if (t < 272) {
      int q = t / 17, c = t - q * 17;
      float s = 0.0f;
      for (int r = q; r < 512; r += 16) s += wpart[r * 17 + c];
      red[t] = s;
    }
    __syncthreads();
    if (t < 17) {
      float s = 0.0f;
#pragma unroll
      for (int q = 0; q < 16; q++) s += red[q * 17 + t];
      wsf[t] = s;
    }
    return;
  }
  if (blk >= 513) {  // ---- enc: xe + dinv for 16 rows (h0 from partials, fp32) ----
    float h0f[8];
#pragma unroll
    for (int q2 = 0; q2 < 8; q2++) {
      int c = lane * 8 + q2;
      float v = fcb[c];
#pragma unroll
      for (int q = 0; q < 8; q++) v += h0p[q * 512 + c];
      h0f[q2] = fmaxf(v, 0.0f);
    }
    int j0 = (blk - 513) * 16 + wave * 2;
#pragma unroll
    for (int rr = 0; rr < 2; rr++) {
      int j = j0 + rr;
      const float* wp = &msgw[j * 512 + lane * 8];
      float4 w0 = *(const float4*)(wp);
      float4 w1 = *(const float4*)(wp + 4);
      float s = w0.x * h0f[0] + w0.y * h0f[1] + w0.z * h0f[2] + w0.w * h0f[3] +
                w1.x * h0f[4] + w1.y * h0f[5] + w1.z * h0f[6] + w1.w * h0f[7];
      s = wsum64(s);
      if (lane == 0) {
        float dj = rsqrtf((float)g_cnt[j] + 1.0f);
        dinv[j] = dj;
        xe[j] = make_float2(dj * x_msg[j], dj * (s + msgb[j]));
      }
    }
    return;
  }
  // stage W2A once per block
  for (int i = t; i < 2304; i += 512)
    *(short8*)&w2a[i * 8] = *(const short8*)&w2abf[i * 8];
  __syncthreads();
  int tr = blk >> 5, tc = blk & 31;
  {  // ---- conv2 GEMM for this block's 16 images (A from LDS) ----
    int nlb = wave * 32;
    int nbase = tr * 256 + nlb;
    float4v z = {0.0f, 0.0f, 0.0f, 0.0f};
    float4v acc00 = z, acc01 = z, acc02 = z, acc03 = z;
    float4v acc10 = z, acc11 = z, acc12 = z, acc13 = z;
#pragma unroll
    for (int ks = 0; ks < 9; ks++) {
      int ko = ks * 32 + quad * 8;
      short8 a0 = *(const short8*)&w2a[(0 * 16 + m) * 288 + ko];
      short8 a1 = *(const short8*)&w2a[(1 * 16 + m) * 288 + ko];
      short8 a2 = *(const short8*)&w2a[(2 * 16 + m) * 288 + ko];
      short8 a3 = *(const short8*)&w2a[(3 * 16 + m) * 288 + ko];
      short8 b0 = *(const short8*)&c1b[(nbase + m) * 288 + ko];
      short8 b1 = *(const short8*)&c1b[(nbase + 16 + m) * 288 + ko];
      acc00 = __builtin_amdgcn_mfma_f32_16x16x32_bf16(a0, b0, acc00, 0, 0, 0);
      acc01 = __builtin_amdgcn_mfma_f32_16x16x32_bf16(a1, b0, acc01, 0, 0, 0);
      acc02 = __builtin_amdgcn_mfma_f32_16x16x32_bf16(a2, b0, acc02, 0, 0, 0);
      acc03 = __builtin_amdgcn_mfma_f32_16x16x32_bf16(a3, b0, acc03, 0, 0, 0);
      acc10 = __builtin_amdgcn_mfma_f32_16x16x32_bf16(a0, b1, acc10, 0, 0, 0);
      acc11 = __builtin_amdgcn_mfma_f32_16x16x32_bf16(a1, b1, acc11, 0, 0, 0);
      acc12 = __builtin_amdgcn_mfma_f32_16x16x32_bf16(a2, b1, acc12, 0, 0, 0);
      acc13 = __builtin_amdgcn_mfma_f32_16x16x32_bf16(a3, b1, acc13, 0, 0, 0);
    }
    float4v accs[2][4] = {{acc00, acc01, acc02, acc03}, {acc10, acc11, acc12, acc13}};
#pragma unroll
    for (int nt = 0; nt < 2; nt++) {
#pragma unroll
      for (int mt = 0; mt < 4; mt++) {
#pragma unroll
        for (int r = 0; r < 4; r++) {
          int oc = mt * 16 + quad * 4 + r;
          int nl = nlb + nt * 16 + m;
          hs[(nl >> 4) * 1024 + oc * 16 + (nl & 15)] =
              f2bf(fmaxf(accs[nt][mt][r] + c2b[oc], 0.0f));
        }
      }
    }
  }
  __syncthreads();
  {  // ---- FC tile: A = hs (LDS), B = fcwbf[tc]; 8-way K split, reduce in LDS ----
    const unsigned short* ap = &hs[m * 1024 + wave * 128 + quad * 8];
    const unsigned short* bp = &fcwbf[(tc * 16 + m) * 1024 + wave * 128 + quad * 8];
    float4v acc = {0.0f, 0.0f, 0.0f, 0.0f};
#pragma unroll
    for (int ks = 0; ks < 4; ks++) {
      short8 av = *(const short8*)(ap + ks * 32);
      short8 bv = *(const short8*)(bp + ks * 32);
      acc = __builtin_amdgcn_mfma_f32_16x16x32_bf16(av, bv, acc, 0, 0, 0);
    }
#pragma unroll
    for (int r = 0; r < 4; r++) red[wave * 256 + (quad * 4 + r) * 16 + m] = acc[r];
    __syncthreads();
    if (t < 256) {
      float s = 0.0f;
#pragma unroll
      for (int w = 0; w < 8; w++) s += red[w * 256 + t];
      int gr = tr * 16 + (t >> 4);
      int gc = tc * 16 + (t & 15);
      hidden[gr * 512 + gc] = fmaxf(s + fcb[gc], 0.0f);
    }
  }
}

// ---------------- K3 k_hg: head (0..63) | GCN1 gather (64..575) ----------------
__global__ __launch_bounds__(512, 2) void k_hg(
    const float* __restrict__ hidden, const float* __restrict__ muw,
    const float* __restrict__ mub, const int* __restrict__ action,
    const int* __restrict__ csr, const float* __restrict__ dinv,
    const float2* __restrict__ xe, const float* __restrict__ g1w,
    const float* __restrict__ g1b, float* gbuf2, float* out) {
  __shared__ float muT[10752];
  __shared__ float hrows[2048];
  int t = threadIdx.x, blk = blockIdx.x;
  int wave = t >> 6, lane = t & 63;
  if (blk < 64) {  // head: 4 batch rows per block
    int b0 = blk * 4;
    for (int i = t; i < 10752; i += 512) {
      int a = i >> 9, k = i & 511;
      muT[k * 21 + a] = muw[i];
    }
    for (int i = t; i < 2048; i += 512) hrows[i] = hidden[b0 * 512 + i];
    __syncthreads();
    if (wave < 4) {
      int b = b0 + wave;
      float logit = -1e30f;
      if (lane < NACT) {
        float acc = mub[lane];
        const float* hr = &hrows[wave * 512];
        for (int k = 0; k < 512; k++) acc += hr[k] * muT[k * 21 + lane];
        logit = acc;
      }
      float mx = logit;
#pragma unroll
      for (int s = 32; s > 0; s >>= 1) mx = fmaxf(mx, __shfl_xor(mx, s, 64));
      float e = (lane < NACT) ? __expf(logit - mx) : 0.0f;
      float se = wsum64(e);
      float swl = wsum64(e * logit);
      float lse = mx + __logf(se);
      int act = action[b];
      if (lane == 0) {
        out[b] = (float)act;                  // action passthrough
        out[8704 + b] = lse - swl / se;       // entropy
      }
      if (lane == act) out[8448 + b] = logit - lse;  // log_prob
    }
  } else {  // GCN1 gather: 2 rows per wave
    int wg = (blk - 64) * 8 + wave;  // 0..4095
#pragma unroll
    for (int rr = 0; rr < 2; rr++) {
      int i = wg * 2 + rr;
      int ci = min(g_cnt[i], CSR_CAP);
      float di = dinv[i];
      float a0 = 0.0f, a1 = 0.0f;
      for (int e = lane; e < ci; e += 64) {
        int s = csr[i * CSR_CAP + e];
        float2 v = xe[s];
        a0 += v.x;
        a1 += v.y;
      }
      float2 vi = xe[i];
      float f0 = (wsum64(a0) + vi.x) * di;
      float f1 = (wsum64(a1) + vi.y) * di;
      if (lane < 16) {
        float gv = fmaxf(f0 * g1w[lane] + f1 * g1w[16 + lane] + g1b[lane], 0.0f);
        gbuf2[i * 16 + lane] = di * gv;
      }
    }
  }
}

// ---------------- K4 k_msg: GCN2 gather + MFMA scores + sum-exp (16 rows/block, 512 blocks) ----------------
__global__ __launch_bounds__(512, 2) void k_msg(
    const int* __restrict__ csr, const float* __restrict__ dinv,
    const float* __restrict__ gbuf2, const float* __restrict__ wsf,
    const unsigned short* __restrict__ w2t, const float* __restrict__ g2b, float* out) {
  __shared__ __align__(16) unsigned short vbf[256];
  __shared__ float vf[256];
  __shared__ float pl[2048];
  __shared__ float sl[128];
  __shared__ float wsfs[17];
  int t = threadIdx.x, blk = blockIdx.x;
  int wave = t >> 6, lane = t & 63;
  int rowbase = blk * 16;
  if (t < 17) wsfs[t] = wsf[t];
  {  // gather 16 V rows
    int eq = lane >> 4, c = lane & 15;
#pragma unroll
    for (int rr = 0; rr < 2; rr++) {
      int il = wave * 2 + rr;
      int i = rowbase + il;
      int ci = min(g_cnt[i], CSR_CAP);
      float di = dinv[i];
      float acc = (eq == 0) ? gbuf2[i * 16 + c] : 0.0f;
      for (int e = eq; e < ci; e += 4) {
        int s = csr[i * CSR_CAP + e];
        acc += gbuf2[s * 16 + c];
      }
      acc *= di;
      acc += __shfl_xor(acc, 16, 64);
      acc += __shfl_xor(acc, 32, 64);
      if (eq == 0) {
        vf[il * 16 + c] = acc;
        vbf[il * 16 + c] = f2bf(acc * LOG2E);
      }
    }
  }
  __syncthreads();
  float myMean = 0.0f;
  if (t < 16) {
    float dot = 0.0f;
#pragma unroll
    for (int c = 0; c < 16; c++) dot += vf[t * 16 + c] * wsfs[c];
    myMean = (dot + wsfs[16]) * (1.0f / 8192.0f);
  }
  {  // scores via MFMA + exp2
    int quad = lane >> 4, n = lane & 15;
    int k8 = quad * 8;
    short8 za = {0, 0, 0, 0, 0, 0, 0, 0};
    short8 a1 = za;
    if (quad < 2) a1 = *(const short8*)&vbf[n * 16 + k8];
    float sacc[4];
#pragma unroll
    for (int q = 0; q < 4; q++) sacc[q] = 0.0f;
    int colb = wave * 1024 + n;
    for (int tp = 0; tp < 64; tp += 2) {
      int col1 = colb + tp * 16;
      int col2 = col1 + 16;
      short8 b1 = za, b2 = za;
      if (quad < 2) {
        b1 = *(const short8*)&w2t[col1 * 16 + k8];
        b2 = *(const short8*)&w2t[col2 * 16 + k8];
      }
      float bb1 = g2b[col1] * LOG2E, bb2 = g2b[col2] * LOG2E;
      float4v c1 = {bb1, bb1, bb1, bb1};
      float4v c2 = {bb2, bb2, bb2, bb2};
      float4v s11 = __builtin_amdgcn_mfma_f32_16x16x32_bf16(a1, b1, c1, 0, 0, 0);
      float4v s12 = __builtin_amdgcn_mfma_f32_16x16x32_bf16(a1, b2, c2, 0, 0, 0);
#pragma unroll
      for (int r = 0; r < 4; r++) sacc[r] += EXP2F(s11[r]) + EXP2F(s12[r]);
    }
#pragma unroll
    for (int q = 0; q < 4; q++) {
      int rl = quad * 4 + q;
      pl[rl * 128 + wave * 16 + n] = sacc[q];
    }
  }
  __syncthreads();
  if (t < 128) {
    int r = t >> 3, seg = t & 7;
    int base = r * 128 + seg * 16;
    float ll = 0.0f;
#pragma unroll
    for (int i = 0; i < 16; i++) ll += pl[base + i];
    sl[r * 8 + seg] = ll;
  }
  __syncthreads();
  if (t < 16) {
    float ll = 0.0f;
#pragma unroll
    for (int i = 0; i < 8; i++) ll += sl[t * 8 + i];
    out[256 + rowbase + t] = myMean - __logf(ll);
  }
  // PROTOCOL: restore g_cnt == 0 for the next iteration (own rows only; all reads done).
  if (t < 16) g_cnt[rowbase + t] = 0;
}

extern "C" void kernel_launch(void* const* d_in, const int* in_sizes, int n_in,
                              void* d_out, int out_size, void* d_ws, size_t ws_size,
                              hipStream_t stream) {
  const float* x     = (const float*)d_in[0];
  const float* x_msg = (const float*)d_in[1];
  const int*   edges = (const int*)d_in[2];
  const int*   action= (const int*)d_in[3];
  const float* c1w   = (const float*)d_in[4];
  const float* c1bb  = (const float*)d_in[5];
  const float* c2w   = (const float*)d_in[6];
  const float* c2b   = (const float*)d_in[7];
  const float* fcw   = (const float*)d_in[8];
  const float* fcb   = (const float*)d_in[9];
  const float* muw   = (const float*)d_in[10];
  const float* mub   = (const float*)d_in[11];
  const float* msgw  = (const float*)d_in[12];
  const float* msgb  = (const float*)d_in[13];
  const float* g1w   = (const float*)d_in[14];
  const float* g1b   = (const float*)d_in[15];
  const float* g2w   = (const float*)d_in[16];
  const float* g2b   = (const float*)d_in[17];
  float* out = (float*)d_out;  // reference outputs are fp32

  float* ws     = (float*)d_ws;
  unsigned short* fcwbf   = (unsigned short*)(ws + 131072); // 524288 bf16 = 262144 f
  float* hidden = ws + 393216;           // 131072
  float2* xe    = (float2*)(ws + 524288);  // 8192 float2 -> ends 540672
  float* dinv   = ws + 540672;           // 8192 -> ends 548864
  float* gbuf2  = ws + 548864;           // 131072
  float* wpart  = ws + 679936;           // 8704
  unsigned short* w2t = (unsigned short*)(ws + 688640);     // 131072 bf16 = 65536 f
  int*   csr    = (int*)(ws + 762368);   // 1048576 ints -> ends at float-offset 1810944
  float* wsf    = ws + 1810944;          // 17
  unsigned short* c1b   = (unsigned short*)(ws + 1810964);  // 4096*288 bf16 = 589824 f
  unsigned short* w2abf = (unsigned short*)(ws + 2400788);  // 64*288 bf16 = 9216 f
  float* h0p    = ws + 2410004;          // 8*512 = 4096

  k_ip <<<1324, 512, 0, stream>>>(x, c1w, c1bb, c2w, c2b, fcw, g2w, g2b, edges,
                                  c1b, w2abf, csr, fcwbf, w2t, wpart, h0p);
  k_cf <<<1025, 512, 0, stream>>>(c1b, w2abf, c2b, fcwbf, fcb, wpart, h0p,
                                  msgw, msgb, x_msg, hidden, wsf, xe, dinv);
  k_hg <<<576, 512, 0, stream>>>(hidden, muw, mub, action, csr, dinv, xe,
                                 g1w, g1b, gbuf2, out);
  k_msg<<<512, 512, 0, stream>>>(csr, dinv, gbuf2, wsf, w2t, g2b, out);
}

// Round 11
// 170.363 us; speedup vs baseline: 1.0923x; 1.0923x over previous
//
#include <hip/hip_runtime.h>
#include <hip/hip_bf16.h>

// Problem constants
#define NB 256
#define NACT 21
#define NA 8192
#define NE 262144
#define CSR_CAP 128
#define LOG2E 1.44269504f

#if __has_builtin(__builtin_amdgcn_exp2f)
#define EXP2F(x) __builtin_amdgcn_exp2f(x)
#else
#define EXP2F(x) exp2f(x)
#endif

typedef __attribute__((ext_vector_type(8))) short short8;
typedef __attribute__((ext_vector_type(4))) float float4v;

__device__ inline float wsum64(float v) {
#pragma unroll
  for (int m = 32; m > 0; m >>= 1) v += __shfl_xor(v, m, 64);
  return v;
}

__device__ inline unsigned short f2bf(float f) {
  union { __hip_bfloat16 h; unsigned short u; } cv;
  cv.h = __float2bfloat16(f);
  return cv.u;
}

// ---------------- K_A: conv1+im2col (0..255) | cnt zero (256..271) | c2w cvt (272..307)
// ----------------      | prep fcw/w2t/wpart (308..819)  -- all independent ----------------
__global__ __launch_bounds__(512, 2) void k_ip(
    const float* __restrict__ x, const float* __restrict__ c1w, const float* __restrict__ c1b_,
    const float* __restrict__ c2w, const float* __restrict__ fcw,
    const float* __restrict__ g2w, const float* __restrict__ g2b,
    unsigned short* c1b, unsigned short* w2abf, int* cnt,
    unsigned short* fcwbf, unsigned short* w2t, float* wpart) {
  __shared__ float sm[3437];  // conv: xs[845] w1s[1440] c1s[1152]; prep: red[16][17]+b2s[16]
  int t = threadIdx.x, b = blockIdx.x;
  if (b >= 308) {  // ---- prep (non-CSR): fcw->bf16, W2 transpose + partials ----
    float (*red)[17] = (float(*)[17])sm;
    float* b2s = sm + 272;
    int blk = b - 308;
    {  // fcw -> bf16: 2 floats per thread
      int base = (blk * 512 + t) * 2;
      float2 v = *(const float2*)&fcw[base];
      fcwbf[base + 0] = f2bf(v.x);
      fcwbf[base + 1] = f2bf(v.y);
    }
    {  // W2: block owns 16 cols; w2t[j][k] = W2[k][j] bf16; column partial sums
      if (t < 256) {
        int jj = t >> 4, k = t & 15;
        int j = blk * 16 + jj;
        float w = g2w[k * 8192 + j];
        w2t[j * 16 + k] = f2bf(w);
        red[jj][k] = w;
      }
      if (t < 16) b2s[t] = g2b[blk * 16 + t];
      __syncthreads();
      if (t < 16) {
        float s = 0.0f;
#pragma unroll
        for (int q = 0; q < 16; q++) s += red[q][t];
        wpart[blk * 17 + t] = s;
      } else if (t == 16) {
        float s = 0.0f;
#pragma unroll
        for (int q = 0; q < 16; q++) s += b2s[q];
        wpart[blk * 17 + 16] = s;
      }
    }
    return;
  }
  if (b >= 272) {  // c2w -> bf16 (64*288 = 18432 values)
    int i = (b - 272) * 512 + t;
    w2abf[i] = f2bf(c2w[i]);
    return;
  }
  if (b >= 256) {  // zero cnt
    cnt[(b - 256) * 512 + t] = 0;
    return;
  }
  // ---- conv1 for image b + im2col write ----
  float* xs = sm;
  float* w1s = sm + 845;
  float* c1s = sm + 2285;
  for (int i = t; i < 845; i += 512) xs[i] = x[b * 845 + i];
  for (int i = t; i < 1440; i += 512) w1s[i] = c1w[i];
  __syncthreads();
  for (int idx = t; idx < 1152; idx += 512) {
    int oc = idx / 36, p = idx - oc * 36;
    int oy = p / 6, ox = p - oy * 6;
    float acc = c1b_[oc];
    const float* wp = &w1s[oc * 45];
#pragma unroll
    for (int ic = 0; ic < 5; ic++)
#pragma unroll
      for (int ky = 0; ky < 3; ky++)
#pragma unroll
        for (int kx = 0; kx < 3; kx++)
          acc += xs[ic * 169 + (oy * 2 + ky) * 13 + ox * 2 + kx] * wp[ic * 9 + ky * 3 + kx];
    c1s[idx] = fmaxf(acc, 0.0f);
  }
  __syncthreads();
  for (int i = t; i < 4608; i += 512) {  // im2col: c1b[(b*16+p)*288 + k]
    int p = i / 288, k = i - p * 288;
    int ic = k / 9, r = k - ic * 9;
    int ky = r / 3, kx = r - ky * 3;
    int oy = p >> 2, ox = p & 3;
    c1b[b * 4608 + i] = f2bf(c1s[ic * 36 + (oy + ky) * 6 + ox + kx]);
  }
}

// ---------------- K_B: conv2+fc fused tile (0..511) | CSR (512..1023) | wsf (1024) ----------------
// Fused block (tr,tc): stage W2A in LDS, conv2 GEMM for images tr*16..+16 -> LDS, FC tile -> hidden.
__global__ __launch_bounds__(512, 2) void k_cf(
    const int* __restrict__ edges, int* cnt, int* csr,
    const unsigned short* __restrict__ c1b, const unsigned short* __restrict__ w2abf,
    const float* __restrict__ c2b, const unsigned short* __restrict__ fcwbf,
    const float* __restrict__ fcb, const float* __restrict__ wpart,
    float* hidden, float* wsf) {
  __shared__ __align__(16) unsigned short hs[16384];   // h tile [16 imgs][1024] bf16 (32 KB)
  __shared__ __align__(16) unsigned short w2a[18432];  // staged W2A [64][288] bf16 (36 KB)
  __shared__ float red[2048];                          // [8][256] fc reduce / wsf parts (8 KB)
  int t = threadIdx.x, blk = blockIdx.x;
  int wave = t >> 6, lane = t & 63;
  int m = lane & 15, quad = lane >> 4;
  if (blk >= 1024) {  // ---- wsf reduce ----
    if (t < 272) {
      int q = t / 17, c = t - q * 17;
      float s = 0.0f;
      for (int r = q; r < 512; r += 16) s += wpart[r * 17 + c];
      red[t] = s;
    }
    __syncthreads();
    if (t < 17) {
      float s = 0.0f;
#pragma unroll
      for (int q = 0; q < 16; q++) s += red[q * 17 + t];
      wsf[t] = s;
    }
    return;
  }
  if (blk >= 512) {  // ---- CSR build (cnt zeroed in K_A) ----
    int e = (blk - 512) * 512 + t;
    int s = edges[2 * e], d = edges[2 * e + 1];
    int slot = atomicAdd(&cnt[d], 1);
    if (slot < CSR_CAP) csr[d * CSR_CAP + slot] = s;
    return;
  }
  // stage W2A once per block (was: every wave re-read 36 KB from L2)
  for (int i = t; i < 2304; i += 512)
    *(short8*)&w2a[i * 8] = *(const short8*)&w2abf[i * 8];
  __syncthreads();
  int tr = blk >> 5, tc = blk & 31;
  {  // ---- conv2 GEMM for this block's 16 images (A from LDS) ----
    int nlb = wave * 32;            // local n base (n = img_local*16 + pos)
    int nbase = tr * 256 + nlb;     // global n
    float4v z = {0.0f, 0.0f, 0.0f, 0.0f};
    float4v acc00 = z, acc01 = z, acc02 = z, acc03 = z;
    float4v acc10 = z, acc11 = z, acc12 = z, acc13 = z;
#pragma unroll
    for (int ks = 0; ks < 9; ks++) {
      int ko = ks * 32 + quad * 8;
      short8 a0 = *(const short8*)&w2a[(0 * 16 + m) * 288 + ko];
      short8 a1 = *(const short8*)&w2a[(1 * 16 + m) * 288 + ko];
      short8 a2 = *(const short8*)&w2a[(2 * 16 + m) * 288 + ko];
      short8 a3 = *(const short8*)&w2a[(3 * 16 + m) * 288 + ko];
      short8 b0 = *(const short8*)&c1b[(nbase + m) * 288 + ko];
      short8 b1 = *(const short8*)&c1b[(nbase + 16 + m) * 288 + ko];
      acc00 = __builtin_amdgcn_mfma_f32_16x16x32_bf16(a0, b0, acc00, 0, 0, 0);
      acc01 = __builtin_amdgcn_mfma_f32_16x16x32_bf16(a1, b0, acc01, 0, 0, 0);
      acc02 = __builtin_amdgcn_mfma_f32_16x16x32_bf16(a2, b0, acc02, 0, 0, 0);
      acc03 = __builtin_amdgcn_mfma_f32_16x16x32_bf16(a3, b0, acc03, 0, 0, 0);
      acc10 = __builtin_amdgcn_mfma_f32_16x16x32_bf16(a0, b1, acc10, 0, 0, 0);
      acc11 = __builtin_amdgcn_mfma_f32_16x16x32_bf16(a1, b1, acc11, 0, 0, 0);
      acc12 = __builtin_amdgcn_mfma_f32_16x16x32_bf16(a2, b1, acc12, 0, 0, 0);
      acc13 = __builtin_amdgcn_mfma_f32_16x16x32_bf16(a3, b1, acc13, 0, 0, 0);
    }
    float4v accs[2][4] = {{acc00, acc01, acc02, acc03}, {acc10, acc11, acc12, acc13}};
#pragma unroll
    for (int nt = 0; nt < 2; nt++) {
#pragma unroll
      for (int mt = 0; mt < 4; mt++) {
#pragma unroll
        for (int r = 0; r < 4; r++) {
          int oc = mt * 16 + quad * 4 + r;       // D row = oc
          int nl = nlb + nt * 16 + m;            // local n
          hs[(nl >> 4) * 1024 + oc * 16 + (nl & 15)] =
              f2bf(fmaxf(accs[nt][mt][r] + c2b[oc], 0.0f));
        }
      }
    }
  }
  __syncthreads();
  {  // ---- FC tile: A = hs (LDS), B = fcwbf[tc]; 8-way K split, reduce in LDS ----
    const unsigned short* ap = &hs[m * 1024 + wave * 128 + quad * 8];
    const unsigned short* bp = &fcwbf[(tc * 16 + m) * 1024 + wave * 128 + quad * 8];
    float4v acc = {0.0f, 0.0f, 0.0f, 0.0f};
#pragma unroll
    for (int ks = 0; ks < 4; ks++) {
      short8 av = *(const short8*)(ap + ks * 32);
      short8 bv = *(const short8*)(bp + ks * 32);
      acc = __builtin_amdgcn_mfma_f32_16x16x32_bf16(av, bv, acc, 0, 0, 0);
    }
#pragma unroll
    for (int r = 0; r < 4; r++) red[wave * 256 + (quad * 4 + r) * 16 + m] = acc[r];
    __syncthreads();
    if (t < 256) {
      float s = 0.0f;
#pragma unroll
      for (int w = 0; w < 8; w++) s += red[w * 256 + t];
      int gr = tr * 16 + (t >> 4);
      int gc = tc * 16 + (t & 15);
      hidden[gr * 512 + gc] = fmaxf(s + fcb[gc], 0.0f);
    }
  }
}

// ---------------- K_C: head (0..63) | enc (64..511) | dinv/xe.x (512..527) ----------------
__global__ __launch_bounds__(512, 2) void k_he(
    const float* __restrict__ hidden, const float* __restrict__ muw,
    const float* __restrict__ mub, const float* __restrict__ msgw,
    const float* __restrict__ msgb, const int* __restrict__ cnt,
    const float* __restrict__ x_msg, const int* __restrict__ action,
    float2* xe, float* dinv, float* out) {
  __shared__ float muT[10752];
  __shared__ float hrows[2048];
  int t = threadIdx.x, blk = blockIdx.x;
  int wave = t >> 6, lane = t & 63;
  if (blk >= 512) {  // dinv + xe.x = dinv*x_msg
    int i = (blk - 512) * 512 + t;
    float d = rsqrtf((float)cnt[i] + 1.0f);
    dinv[i] = d;
    xe[i].x = d * x_msg[i];
    return;
  }
  if (blk < 64) {  // head: 4 batch rows per block
    int b0 = blk * 4;
    for (int i = t; i < 10752; i += 512) {
      int a = i >> 9, k = i & 511;
      muT[k * 21 + a] = muw[i];
    }
    for (int i = t; i < 2048; i += 512) hrows[i] = hidden[b0 * 512 + i];
    __syncthreads();
    if (wave < 4) {
      int b = b0 + wave;
      float logit = -1e30f;
      if (lane < NACT) {
        float acc = mub[lane];
        const float* hr = &hrows[wave * 512];
        for (int k = 0; k < 512; k++) acc += hr[k] * muT[k * 21 + lane];
        logit = acc;
      }
      float mx = logit;
#pragma unroll
      for (int s = 32; s > 0; s >>= 1) mx = fmaxf(mx, __shfl_xor(mx, s, 64));
      float e = (lane < NACT) ? __expf(logit - mx) : 0.0f;
      float se = wsum64(e);
      float swl = wsum64(e * logit);
      float lse = mx + __logf(se);
      int act = action[b];
      if (lane == 0) {
        out[b] = (float)act;                  // action passthrough
        out[8704 + b] = lse - swl / se;       // entropy
      }
      if (lane == act) out[8448 + b] = logit - lse;  // log_prob
    }
  } else {  // enc: xe[j].y = rsqrt(cnt[j]+1) * (hidden[0].msg_w[j] + msgb[j])
    int wg = (blk - 64) * 8 + wave;  // 0..3583
    for (int j = wg; j < NA; j += 3584) {
      const float* wp = &msgw[j * 512 + lane * 8];
      float4 w0 = *(const float4*)(wp);
      float4 w1 = *(const float4*)(wp + 4);
      float4 h0 = *(const float4*)&hidden[lane * 8];
      float4 h1 = *(const float4*)&hidden[lane * 8 + 4];
      float s = w0.x * h0.x + w0.y * h0.y + w0.z * h0.z + w0.w * h0.w +
                w1.x * h1.x + w1.y * h1.y + w1.z * h1.z + w1.w * h1.w;
      s = wsum64(s);
      if (lane == 0) xe[j].y = rsqrtf((float)cnt[j] + 1.0f) * (s + msgb[j]);
    }
  }
}

// ---------------- K_D: GCN1 gather (2 rows per wave, 512 blocks; packed xe loads) ----------------
__global__ __launch_bounds__(512, 4) void k_g1(
    const int* __restrict__ cnt, const int* __restrict__ csr,
    const float* __restrict__ dinv, const float2* __restrict__ xe,
    const float* __restrict__ g1w, const float* __restrict__ g1b, float* gbuf2) {
  int t = threadIdx.x, blk = blockIdx.x;
  int wave = t >> 6, lane = t & 63;
  int wg = blk * 8 + wave;  // 0..4095
#pragma unroll
  for (int rr = 0; rr < 2; rr++) {
    int i = wg * 2 + rr;
    int ci = min(cnt[i], CSR_CAP);
    float di = dinv[i];
    float a0 = 0.0f, a1 = 0.0f;
    for (int e = lane; e < ci; e += 64) {
      int s = csr[i * CSR_CAP + e];
      float2 v = xe[s];  // one 8B load instead of two 4B random loads
      a0 += v.x;
      a1 += v.y;
    }
    float2 vi = xe[i];
    float f0 = (wsum64(a0) + vi.x) * di;
    float f1 = (wsum64(a1) + vi.y) * di;
    if (lane < 16) {
      float gv = fmaxf(f0 * g1w[lane] + f1 * g1w[16 + lane] + g1b[lane], 0.0f);
      gbuf2[i * 16 + lane] = di * gv;
    }
  }
}

// ---------------- K_E: GCN2 gather + MFMA scores + sum-exp (16 rows/block, 512 blocks) ----------------
// launch_bounds (512,4): cap VGPR <=128 so the latency-bound gather keeps >=2 blocks/CU resident.
__global__ __launch_bounds__(512, 4) void k_msg(
    const int* __restrict__ cnt, const int* __restrict__ csr,
    const float* __restrict__ dinv, const float* __restrict__ gbuf2,
    const float* __restrict__ wsf, const unsigned short* __restrict__ w2t,
    const float* __restrict__ g2b, float* out) {
  __shared__ __align__(16) unsigned short vbf[256];
  __shared__ float vf[256];
  __shared__ float pl[2048];
  __shared__ float sl[128];
  __shared__ float wsfs[17];
  int t = threadIdx.x, blk = blockIdx.x;
  int wave = t >> 6, lane = t & 63;
  int rowbase = blk * 16;
  if (t < 17) wsfs[t] = wsf[t];
  {  // gather 16 V rows
    int eq = lane >> 4, c = lane & 15;
#pragma unroll
    for (int rr = 0; rr < 2; rr++) {
      int il = wave * 2 + rr;
      int i = rowbase + il;
      int ci = min(cnt[i], CSR_CAP);
      float di = dinv[i];
      float acc = (eq == 0) ? gbuf2[i * 16 + c] : 0.0f;
      for (int e = eq; e < ci; e += 4) {
        int s = csr[i * CSR_CAP + e];
        acc += gbuf2[s * 16 + c];
      }
      acc *= di;
      acc += __shfl_xor(acc, 16, 64);
      acc += __shfl_xor(acc, 32, 64);
      if (eq == 0) {
        vf[il * 16 + c] = acc;
        vbf[il * 16 + c] = f2bf(acc * LOG2E);
      }
    }
  }
  __syncthreads();
  float myMean = 0.0f;
  if (t < 16) {
    float dot = 0.0f;
#pragma unroll
    for (int c = 0; c < 16; c++) dot += vf[t * 16 + c] * wsfs[c];
    myMean = (dot + wsfs[16]) * (1.0f / 8192.0f);
  }
  {  // scores via MFMA + exp2
    int quad = lane >> 4, n = lane & 15;
    int k8 = quad * 8;
    short8 za = {0, 0, 0, 0, 0, 0, 0, 0};
    short8 a1 = za;
    if (quad < 2) a1 = *(const short8*)&vbf[n * 16 + k8];
    float sacc[4];
#pragma unroll
    for (int q = 0; q < 4; q++) sacc[q] = 0.0f;
    int colb = wave * 1024 + n;
    for (int tp = 0; tp < 64; tp += 2) {
      int col1 = colb + tp * 16;
      int col2 = col1 + 16;
      short8 b1 = za, b2 = za;
      if (quad < 2) {
        b1 = *(const short8*)&w2t[col1 * 16 + k8];
        b2 = *(const short8*)&w2t[col2 * 16 + k8];
      }
      float bb1 = g2b[col1] * LOG2E, bb2 = g2b[col2] * LOG2E;
      float4v c1 = {bb1, bb1, bb1, bb1};
      float4v c2 = {bb2, bb2, bb2, bb2};
      float4v s11 = __builtin_amdgcn_mfma_f32_16x16x32_bf16(a1, b1, c1, 0, 0, 0);
      float4v s12 = __builtin_amdgcn_mfma_f32_16x16x32_bf16(a1, b2, c2, 0, 0, 0);
#pragma unroll
      for (int r = 0; r < 4; r++) sacc[r] += EXP2F(s11[r]) + EXP2F(s12[r]);
    }
#pragma unroll
    for (int q = 0; q < 4; q++) {
      int rl = quad * 4 + q;
      pl[rl * 128 + wave * 16 + n] = sacc[q];
    }
  }
  __syncthreads();
  if (t < 128) {
    int r = t >> 3, seg = t & 7;
    int base = r * 128 + seg * 16;
    float ll = 0.0f;
#pragma unroll
    for (int i = 0; i < 16; i++) ll += pl[base + i];
    sl[r * 8 + seg] = ll;
  }
  __syncthreads();
  if (t < 16) {
    float ll = 0.0f;
#pragma unroll
    for (int i = 0; i < 8; i++) ll += sl[t * 8 + i];
    out[256 + rowbase + t] = myMean - __logf(ll);
  }
}

extern "C" void kernel_launch(void* const* d_in, const int* in_sizes, int n_in,
                              void* d_out, int out_size, void* d_ws, size_t ws_size,
                              hipStream_t stream) {
  const float* x     = (const float*)d_in[0];
  const float* x_msg = (const float*)d_in[1];
  const int*   edges = (const int*)d_in[2];
  const int*   action= (const int*)d_in[3];
  const float* c1w   = (const float*)d_in[4];
  const float* c1bb  = (const float*)d_in[5];
  const float* c2w   = (const float*)d_in[6];
  const float* c2b   = (const float*)d_in[7];
  const float* fcw   = (const float*)d_in[8];
  const float* fcb   = (const float*)d_in[9];
  const float* muw   = (const float*)d_in[10];
  const float* mub   = (const float*)d_in[11];
  const float* msgw  = (const float*)d_in[12];
  const float* msgb  = (const float*)d_in[13];
  const float* g1w   = (const float*)d_in[14];
  const float* g1b   = (const float*)d_in[15];
  const float* g2w   = (const float*)d_in[16];
  const float* g2b   = (const float*)d_in[17];
  float* out = (float*)d_out;  // reference outputs are fp32

  float* ws     = (float*)d_ws;
  unsigned short* fcwbf   = (unsigned short*)(ws + 131072); // 524288 bf16 = 262144 f
  float* hidden = ws + 393216;           // 131072
  float2* xe    = (float2*)(ws + 524288);  // 8192 float2 = 16384 f -> ends 540672
  float* dinv   = ws + 540672;           // 8192 -> ends 548864
  float* gbuf2  = ws + 548864;           // 131072
  float* wpart  = ws + 679936;           // 8704
  unsigned short* w2t = (unsigned short*)(ws + 688640);     // 131072 bf16 = 65536 f
  int*   cnt    = (int*)(ws + 754176);   // 8192 ints
  int*   csr    = (int*)(ws + 762368);   // 1048576 ints -> ends at float-offset 1810944
  float* wsf    = ws + 1810944;          // 17
  unsigned short* c1b   = (unsigned short*)(ws + 1810964);  // 4096*288 bf16 = 589824 f
  unsigned short* w2abf = (unsigned short*)(ws + 2400788);  // 64*288 bf16 = 9216 f

  k_ip <<<820, 512, 0, stream>>>(x, c1w, c1bb, c2w, fcw, g2w, g2b,
                                 c1b, w2abf, cnt, fcwbf, w2t, wpart);
  k_cf <<<1025, 512, 0, stream>>>(edges, cnt, csr, c1b, w2abf, c2b,
                                  fcwbf, fcb, wpart, hidden, wsf);
  k_he <<<528, 512, 0, stream>>>(hidden, muw, mub, msgw, msgb, cnt, x_msg,
                                 action, xe, dinv, out);
  k_g1 <<<512, 512, 0, stream>>>(cnt, csr, dinv, xe, g1w, g1b, gbuf2);
  k_msg<<<512, 512, 0, stream>>>(cnt, csr, dinv, gbuf2, wsf, w2t, g2b, out);
}

// Round 12
// 165.236 us; speedup vs baseline: 1.1262x; 1.0310x over previous
//
#include <hip/hip_runtime.h>
#include <hip/hip_bf16.h>

// Problem constants
#define NB 256
#define NACT 21
#define NA 8192
#define NE 262144
#define CSR_CAP 128
#define LOG2E 1.44269504f

#if __has_builtin(__builtin_amdgcn_exp2f)
#define EXP2F(x) __builtin_amdgcn_exp2f(x)
#else
#define EXP2F(x) exp2f(x)
#endif

typedef __attribute__((ext_vector_type(8))) short short8;
typedef __attribute__((ext_vector_type(4))) float float4v;

__device__ inline float wsum64(float v) {
#pragma unroll
  for (int m = 32; m > 0; m >>= 1) v += __shfl_xor(v, m, 64);
  return v;
}

__device__ inline unsigned short f2bf(float f) {
  union { __hip_bfloat16 h; unsigned short u; } cv;
  cv.h = __float2bfloat16(f);
  return cv.u;
}

// ---------------- K_A: conv1+conv2 per image (0..255) | cnt zero (256..271)
// ----------------      | prep fcw/w2t/wpart (272..783)  -- all independent ----------------
// conv block: conv1 -> c1s (LDS) -> im2col bf16 (LDS) -> conv2 via MFMA (4 waves) -> h1024bf.
__global__ __launch_bounds__(512, 2) void k_ip(
    const float* __restrict__ x, const float* __restrict__ c1w, const float* __restrict__ c1b_,
    const float* __restrict__ c2w, const float* __restrict__ c2b, const float* __restrict__ fcw,
    const float* __restrict__ g2w, const float* __restrict__ g2b,
    unsigned short* h1024bf, int* cnt,
    unsigned short* fcwbf, unsigned short* w2t, float* wpart) {
  __shared__ __align__(16) float sm[5744];  // conv: xs[845] w1s[1440] c1s[1152] | c1bf@3440 (2304f=4608ush)
  int t = threadIdx.x, b = blockIdx.x;
  int wave = t >> 6, lane = t & 63;
  if (b >= 272) {  // ---- prep: fcw->bf16, W2 transpose + partials ----
    float (*red)[17] = (float(*)[17])sm;
    float* b2s = sm + 272;
    int blk = b - 272;
    {  // fcw -> bf16: 2 floats per thread
      int base = (blk * 512 + t) * 2;
      float2 v = *(const float2*)&fcw[base];
      fcwbf[base + 0] = f2bf(v.x);
      fcwbf[base + 1] = f2bf(v.y);
    }
    {  // W2: block owns 16 cols; w2t[j][k] = W2[k][j] bf16; column partial sums
      if (t < 256) {
        int jj = t >> 4, k = t & 15;
        int j = blk * 16 + jj;
        float w = g2w[k * 8192 + j];
        w2t[j * 16 + k] = f2bf(w);
        red[jj][k] = w;
      }
      if (t < 16) b2s[t] = g2b[blk * 16 + t];
      __syncthreads();
      if (t < 16) {
        float s = 0.0f;
#pragma unroll
        for (int q = 0; q < 16; q++) s += red[q][t];
        wpart[blk * 17 + t] = s;
      } else if (t == 16) {
        float s = 0.0f;
#pragma unroll
        for (int q = 0; q < 16; q++) s += b2s[q];
        wpart[blk * 17 + 16] = s;
      }
    }
    return;
  }
  if (b >= 256) {  // zero cnt
    cnt[(b - 256) * 512 + t] = 0;
    return;
  }
  // ---- conv1 for image b ----
  float* xs = sm;
  float* w1s = sm + 845;
  float* c1s = sm + 2285;
  unsigned short* c1bf = (unsigned short*)(sm + 3440);  // [16 pos][288 k] bf16, 16B-aligned rows
  for (int i = t; i < 845; i += 512) xs[i] = x[b * 845 + i];
  for (int i = t; i < 1440; i += 512) w1s[i] = c1w[i];
  __syncthreads();
  for (int idx = t; idx < 1152; idx += 512) {
    int oc = idx / 36, p = idx - oc * 36;
    int oy = p / 6, ox = p - oy * 6;
    float acc = c1b_[oc];
    const float* wp = &w1s[oc * 45];
#pragma unroll
    for (int ic = 0; ic < 5; ic++)
#pragma unroll
      for (int ky = 0; ky < 3; ky++)
#pragma unroll
        for (int kx = 0; kx < 3; kx++)
          acc += xs[ic * 169 + (oy * 2 + ky) * 13 + ox * 2 + kx] * wp[ic * 9 + ky * 3 + kx];
    c1s[idx] = fmaxf(acc, 0.0f);
  }
  __syncthreads();
  // ---- im2col to LDS (bf16): c1bf[p*288 + k] ----
  for (int i = t; i < 4608; i += 512) {
    int p = i / 288, k = i - p * 288;
    int ic = k / 9, rr = k - ic * 9;
    int ky = rr / 3, kx = rr - ky * 3;
    int oy = p >> 2, ox = p & 3;
    c1bf[i] = f2bf(c1s[ic * 36 + (oy + ky) * 6 + ox + kx]);
  }
  __syncthreads();
  // ---- conv2 GEMM: M=64(oc) x K=288 x N=16(pos); wave w owns ocs w*16..+16 ----
  if (wave < 4) {
    int m = lane & 15, quad = lane >> 4;
    float4v acc = {0.0f, 0.0f, 0.0f, 0.0f};
#pragma unroll
    for (int ks = 0; ks < 9; ks++) {
      int ko = ks * 32 + quad * 8;
      const float* ar = &c2w[(wave * 16 + m) * 288 + ko];  // convert A on the fly (== old w2abf)
      float4 af0 = *(const float4*)ar;
      float4 af1 = *(const float4*)(ar + 4);
      short8 a;
      a[0] = (short)f2bf(af0.x); a[1] = (short)f2bf(af0.y);
      a[2] = (short)f2bf(af0.z); a[3] = (short)f2bf(af0.w);
      a[4] = (short)f2bf(af1.x); a[5] = (short)f2bf(af1.y);
      a[6] = (short)f2bf(af1.z); a[7] = (short)f2bf(af1.w);
      short8 bv = *(const short8*)&c1bf[m * 288 + ko];
      acc = __builtin_amdgcn_mfma_f32_16x16x32_bf16(a, bv, acc, 0, 0, 0);
    }
#pragma unroll
    for (int r = 0; r < 4; r++) {
      int oc = wave * 16 + quad * 4 + r;  // D row = oc (A side); D col = m = pos (B side)
      h1024bf[b * 1024 + oc * 16 + m] = f2bf(fmaxf(acc[r] + c2b[oc], 0.0f));
    }
  }
}

// ---------------- K_B: FC tiles (0..511) | CSR (512..1023) | wsf (1024) ----------------
__global__ __launch_bounds__(512, 4) void k_cf(
    const int* __restrict__ edges, int* cnt, int* csr,
    const unsigned short* __restrict__ h1024bf, const unsigned short* __restrict__ fcwbf,
    const float* __restrict__ fcb, const float* __restrict__ wpart,
    float* hidden, float* wsf) {
  __shared__ float red[2048];  // [8][256] fc reduce / wsf parts
  int t = threadIdx.x, blk = blockIdx.x;
  int wave = t >> 6, lane = t & 63;
  int m = lane & 15, quad = lane >> 4;
  if (blk >= 1024) {  // ---- wsf reduce ----
    if (t < 272) {
      int q = t / 17, c = t - q * 17;
      float s = 0.0f;
      for (int r = q; r < 512; r += 16) s += wpart[r * 17 + c];
      red[t] = s;
    }
    __syncthreads();
    if (t < 17) {
      float s = 0.0f;
#pragma unroll
      for (int q = 0; q < 16; q++) s += red[q * 17 + t];
      wsf[t] = s;
    }
    return;
  }
  if (blk >= 512) {  // ---- CSR build (cnt zeroed in K_A) ----
    int e = (blk - 512) * 512 + t;
    int s = edges[2 * e], d = edges[2 * e + 1];
    int slot = atomicAdd(&cnt[d], 1);
    if (slot < CSR_CAP) csr[d * CSR_CAP + slot] = s;
    return;
  }
  // ---- FC tile: A = h1024bf (L2), B = fcwbf[tc]; 8-way K split, reduce in LDS ----
  int tr = blk >> 5, tc = blk & 31;
  const unsigned short* ap = &h1024bf[(tr * 16 + m) * 1024 + wave * 128 + quad * 8];
  const unsigned short* bp = &fcwbf[(tc * 16 + m) * 1024 + wave * 128 + quad * 8];
  float4v acc = {0.0f, 0.0f, 0.0f, 0.0f};
#pragma unroll
  for (int ks = 0; ks < 4; ks++) {
    short8 av = *(const short8*)(ap + ks * 32);
    short8 bv = *(const short8*)(bp + ks * 32);
    acc = __builtin_amdgcn_mfma_f32_16x16x32_bf16(av, bv, acc, 0, 0, 0);
  }
#pragma unroll
  for (int r = 0; r < 4; r++) red[wave * 256 + (quad * 4 + r) * 16 + m] = acc[r];
  __syncthreads();
  if (t < 256) {
    float s = 0.0f;
#pragma unroll
    for (int w = 0; w < 8; w++) s += red[w * 256 + t];
    int gr = tr * 16 + (t >> 4);
    int gc = tc * 16 + (t & 15);
    hidden[gr * 512 + gc] = fmaxf(s + fcb[gc], 0.0f);
  }
}

// ---------------- K_C: head (0..63) | enc (64..511) | dinv/xe.x (512..527) ----------------
__global__ __launch_bounds__(512, 2) void k_he(
    const float* __restrict__ hidden, const float* __restrict__ muw,
    const float* __restrict__ mub, const float* __restrict__ msgw,
    const float* __restrict__ msgb, const int* __restrict__ cnt,
    const float* __restrict__ x_msg, const int* __restrict__ action,
    float2* xe, float* dinv, float* out) {
  __shared__ float muT[10752];
  __shared__ float hrows[2048];
  int t = threadIdx.x, blk = blockIdx.x;
  int wave = t >> 6, lane = t & 63;
  if (blk >= 512) {  // dinv + xe.x = dinv*x_msg
    int i = (blk - 512) * 512 + t;
    float d = rsqrtf((float)cnt[i] + 1.0f);
    dinv[i] = d;
    xe[i].x = d * x_msg[i];
    return;
  }
  if (blk < 64) {  // head: 4 batch rows per block
    int b0 = blk * 4;
    for (int i = t; i < 10752; i += 512) {
      int a = i >> 9, k = i & 511;
      muT[k * 21 + a] = muw[i];
    }
    for (int i = t; i < 2048; i += 512) hrows[i] = hidden[b0 * 512 + i];
    __syncthreads();
    if (wave < 4) {
      int b = b0 + wave;
      float logit = -1e30f;
      if (lane < NACT) {
        float acc = mub[lane];
        const float* hr = &hrows[wave * 512];
        for (int k = 0; k < 512; k++) acc += hr[k] * muT[k * 21 + lane];
        logit = acc;
      }
      float mx = logit;
#pragma unroll
      for (int s = 32; s > 0; s >>= 1) mx = fmaxf(mx, __shfl_xor(mx, s, 64));
      float e = (lane < NACT) ? __expf(logit - mx) : 0.0f;
      float se = wsum64(e);
      float swl = wsum64(e * logit);
      float lse = mx + __logf(se);
      int act = action[b];
      if (lane == 0) {
        out[b] = (float)act;                  // action passthrough
        out[8704 + b] = lse - swl / se;       // entropy
      }
      if (lane == act) out[8448 + b] = logit - lse;  // log_prob
    }
  } else {  // enc: xe[j].y = rsqrt(cnt[j]+1) * (hidden[0].msg_w[j] + msgb[j])
    int wg = (blk - 64) * 8 + wave;  // 0..3583
    for (int j = wg; j < NA; j += 3584) {
      const float* wp = &msgw[j * 512 + lane * 8];
      float4 w0 = *(const float4*)(wp);
      float4 w1 = *(const float4*)(wp + 4);
      float4 h0 = *(const float4*)&hidden[lane * 8];
      float4 h1 = *(const float4*)&hidden[lane * 8 + 4];
      float s = w0.x * h0.x + w0.y * h0.y + w0.z * h0.z + w0.w * h0.w +
                w1.x * h1.x + w1.y * h1.y + w1.z * h1.z + w1.w * h1.w;
      s = wsum64(s);
      if (lane == 0) xe[j].y = rsqrtf((float)cnt[j] + 1.0f) * (s + msgb[j]);
    }
  }
}

// ---------------- K_D: GCN1 gather (2 rows per wave, 512 blocks; packed xe loads) ----------------
__global__ __launch_bounds__(512, 4) void k_g1(
    const int* __restrict__ cnt, const int* __restrict__ csr,
    const float* __restrict__ dinv, const float2* __restrict__ xe,
    const float* __restrict__ g1w, const float* __restrict__ g1b, float* gbuf2) {
  int t = threadIdx.x, blk = blockIdx.x;
  int wave = t >> 6, lane = t & 63;
  int wg = blk * 8 + wave;  // 0..4095
#pragma unroll
  for (int rr = 0; rr < 2; rr++) {
    int i = wg * 2 + rr;
    int ci = min(cnt[i], CSR_CAP);
    float di = dinv[i];
    float a0 = 0.0f, a1 = 0.0f;
    for (int e = lane; e < ci; e += 64) {
      int s = csr[i * CSR_CAP + e];
      float2 v = xe[s];  // one 8B load instead of two 4B random loads
      a0 += v.x;
      a1 += v.y;
    }
    float2 vi = xe[i];
    float f0 = (wsum64(a0) + vi.x) * di;
    float f1 = (wsum64(a1) + vi.y) * di;
    if (lane < 16) {
      float gv = fmaxf(f0 * g1w[lane] + f1 * g1w[16 + lane] + g1b[lane], 0.0f);
      gbuf2[i * 16 + lane] = di * gv;
    }
  }
}

// ---------------- K_E: GCN2 gather + MFMA scores + sum-exp (16 rows/block, 512 blocks) ----------------
__global__ __launch_bounds__(512, 4) void k_msg(
    const int* __restrict__ cnt, const int* __restrict__ csr,
    const float* __restrict__ dinv, const float* __restrict__ gbuf2,
    const float* __restrict__ wsf, const unsigned short* __restrict__ w2t,
    const float* __restrict__ g2b, float* out) {
  __shared__ __align__(16) unsigned short vbf[256];
  __shared__ float vf[256];
  __shared__ float pl[2048];
  __shared__ float sl[128];
  __shared__ float wsfs[17];
  int t = threadIdx.x, blk = blockIdx.x;
  int wave = t >> 6, lane = t & 63;
  int rowbase = blk * 16;
  if (t < 17) wsfs[t] = wsf[t];
  {  // gather 16 V rows
    int eq = lane >> 4, c = lane & 15;
#pragma unroll
    for (int rr = 0; rr < 2; rr++) {
      int il = wave * 2 + rr;
      int i = rowbase + il;
      int ci = min(cnt[i], CSR_CAP);
      float di = dinv[i];
      float acc = (eq == 0) ? gbuf2[i * 16 + c] : 0.0f;
      for (int e = eq; e < ci; e += 4) {
        int s = csr[i * CSR_CAP + e];
        acc += gbuf2[s * 16 + c];
      }
      acc *= di;
      acc += __shfl_xor(acc, 16, 64);
      acc += __shfl_xor(acc, 32, 64);
      if (eq == 0) {
        vf[il * 16 + c] = acc;
        vbf[il * 16 + c] = f2bf(acc * LOG2E);
      }
    }
  }
  __syncthreads();
  float myMean = 0.0f;
  if (t < 16) {
    float dot = 0.0f;
#pragma unroll
    for (int c = 0; c < 16; c++) dot += vf[t * 16 + c] * wsfs[c];
    myMean = (dot + wsfs[16]) * (1.0f / 8192.0f);
  }
  {  // scores via MFMA + exp2
    int quad = lane >> 4, n = lane & 15;
    int k8 = quad * 8;
    short8 za = {0, 0, 0, 0, 0, 0, 0, 0};
    short8 a1 = za;
    if (quad < 2) a1 = *(const short8*)&vbf[n * 16 + k8];
    float sacc[4];
#pragma unroll
    for (int q = 0; q < 4; q++) sacc[q] = 0.0f;
    int colb = wave * 1024 + n;
    for (int tp = 0; tp < 64; tp += 2) {
      int col1 = colb + tp * 16;
      int col2 = col1 + 16;
      short8 b1 = za, b2 = za;
      if (quad < 2) {
        b1 = *(const short8*)&w2t[col1 * 16 + k8];
        b2 = *(const short8*)&w2t[col2 * 16 + k8];
      }
      float bb1 = g2b[col1] * LOG2E, bb2 = g2b[col2] * LOG2E;
      float4v c1 = {bb1, bb1, bb1, bb1};
      float4v c2 = {bb2, bb2, bb2, bb2};
      float4v s11 = __builtin_amdgcn_mfma_f32_16x16x32_bf16(a1, b1, c1, 0, 0, 0);
      float4v s12 = __builtin_amdgcn_mfma_f32_16x16x32_bf16(a1, b2, c2, 0, 0, 0);
#pragma unroll
      for (int r = 0; r < 4; r++) sacc[r] += EXP2F(s11[r]) + EXP2F(s12[r]);
    }
#pragma unroll
    for (int q = 0; q < 4; q++) {
      int rl = quad * 4 + q;
      pl[rl * 128 + wave * 16 + n] = sacc[q];
    }
  }
  __syncthreads();
  if (t < 128) {
    int r = t >> 3, seg = t & 7;
    int base = r * 128 + seg * 16;
    float ll = 0.0f;
#pragma unroll
    for (int i = 0; i < 16; i++) ll += pl[base + i];
    sl[r * 8 + seg] = ll;
  }
  __syncthreads();
  if (t < 16) {
    float ll = 0.0f;
#pragma unroll
    for (int i = 0; i < 8; i++) ll += sl[t * 8 + i];
    out[256 + rowbase + t] = myMean - __logf(ll);
  }
}

extern "C" void kernel_launch(void* const* d_in, const int* in_sizes, int n_in,
                              void* d_out, int out_size, void* d_ws, size_t ws_size,
                              hipStream_t stream) {
  const float* x     = (const float*)d_in[0];
  const float* x_msg = (const float*)d_in[1];
  const int*   edges = (const int*)d_in[2];
  const int*   action= (const int*)d_in[3];
  const float* c1w   = (const float*)d_in[4];
  const float* c1bb  = (const float*)d_in[5];
  const float* c2w   = (const float*)d_in[6];
  const float* c2b   = (const float*)d_in[7];
  const float* fcw   = (const float*)d_in[8];
  const float* fcb   = (const float*)d_in[9];
  const float* muw   = (const float*)d_in[10];
  const float* mub   = (const float*)d_in[11];
  const float* msgw  = (const float*)d_in[12];
  const float* msgb  = (const float*)d_in[13];
  const float* g1w   = (const float*)d_in[14];
  const float* g1b   = (const float*)d_in[15];
  const float* g2w   = (const float*)d_in[16];
  const float* g2b   = (const float*)d_in[17];
  float* out = (float*)d_out;  // reference outputs are fp32

  float* ws     = (float*)d_ws;
  unsigned short* h1024bf = (unsigned short*)ws;            // 262144 bf16 = 131072 f
  unsigned short* fcwbf   = (unsigned short*)(ws + 131072); // 524288 bf16 = 262144 f
  float* hidden = ws + 393216;           // 131072
  float2* xe    = (float2*)(ws + 524288);  // 8192 float2 = 16384 f -> ends 540672
  float* dinv   = ws + 540672;           // 8192 -> ends 548864
  float* gbuf2  = ws + 548864;           // 131072
  float* wpart  = ws + 679936;           // 8704
  unsigned short* w2t = (unsigned short*)(ws + 688640);     // 131072 bf16 = 65536 f
  int*   cnt    = (int*)(ws + 754176);   // 8192 ints
  int*   csr    = (int*)(ws + 762368);   // 1048576 ints -> ends at float-offset 1810944
  float* wsf    = ws + 1810944;          // 17

  k_ip <<<784, 512, 0, stream>>>(x, c1w, c1bb, c2w, c2b, fcw, g2w, g2b,
                                 h1024bf, cnt, fcwbf, w2t, wpart);
  k_cf <<<1025, 512, 0, stream>>>(edges, cnt, csr, h1024bf, fcwbf, fcb, wpart,
                                  hidden, wsf);
  k_he <<<528, 512, 0, stream>>>(hidden, muw, mub, msgw, msgb, cnt, x_msg,
                                 action, xe, dinv, out);
  k_g1 <<<512, 512, 0, stream>>>(cnt, csr, dinv, xe, g1w, g1b, gbuf2);
  k_msg<<<512, 512, 0, stream>>>(cnt, csr, dinv, gbuf2, wsf, w2t, g2b, out);
}